// Round 23
// baseline (3712.306 us; speedup 1.0000x reference)
//
#include <hip/hip_runtime.h>
#include <math.h>

constexpr int B = 24, HH = 8;
constexpr int NN = 256, MQ = 64;
constexpr int EC = 364;

#define PI_2 1.5707963267948966f
#define CONV_LDS (36992 * 4)
#define SMALL_LDS (18560 * 4)

// ---- in-block full-row stats: 16 threads/row partials, fixed combine ----
__device__ __forceinline__ void block_stats(const float* __restrict__ sX,
                                            float* __restrict__ scratch,
                                            float* __restrict__ smu,
                                            float* __restrict__ sinv,
                                            int L, int tid) {
  int row = tid >> 4, sub = tid & 15;
  float s = 0.f, q = 0.f;
  for (int l2 = sub; l2 < L; l2 += 16) { float v = sX[row * L + l2]; s += v; q += v * v; }
  scratch[row * 16 + sub] = s;
  scratch[1024 + row * 16 + sub] = q;
  __syncthreads();
  if (tid < 64) {
    float ss = 0.f, qq = 0.f;
    for (int k = 0; k < 16; ++k) { ss += scratch[tid * 16 + k]; qq += scratch[1024 + tid * 16 + k]; }
    float mu = ss / (float)L;
    float var = (qq - ss * mu) / ((float)L - 1.f);
    if (var < 0.f) var = 0.f;
    smu[tid] = mu; sinv[tid] = 1.f / (sqrtf(var) + 1e-6f);
  }
  __syncthreads();
}

// ---- merged prologue: postab + weight transposes -------------------------
__global__ void k_prep(float* __restrict__ tab,
                       const float* __restrict__ e2pw, const float* __restrict__ e1pw,
                       const float* __restrict__ hlw, const float* __restrict__ hgw,
                       const float* __restrict__ e2dw,
                       float* __restrict__ pwT, float* __restrict__ e1pwT,
                       float* __restrict__ hlwT, float* __restrict__ hgwT,
                       float* __restrict__ dwT) {
  int blk = blockIdx.x;
  if (blk < 64) {
    int d = blk, l = threadIdx.x;
    float fr = ((d & 1) == 0) ? powf(10000.f, -(float)d / 64.f)
                              : -powf(10000.f, -(float)(d - 1) / 64.f);
    float ph = (d & 1) ? PI_2 : 0.f;
    tab[d * 256 + l] = sinf(sinf((float)l * fr + ph));
    return;
  }
  int i = (blk - 64) * 256 + threadIdx.x;
  if (i < 12800) { int ce = i >> 6, o = i & 63; pwT[i] = e2pw[o * 200 + ce]; return; }
  i -= 12800;
  if (i < 23296) { int c = i >> 6, o = i & 63; e1pwT[i] = e1pw[o * EC + c]; return; }
  i -= 23296;
  if (i < 8192) {
    int layer = i >> 12, rem = i & 4095;
    int d = rem >> 6, o = rem & 63;
    hlwT[i] = hlw[layer * 4096 + o * 64 + d];
    return;
  }
  i -= 8192;
  if (i < 8192) {
    int layer = i >> 12, rem = i & 4095;
    int d = rem >> 6, o = rem & 63;
    hgwT[i] = hgw[layer * 4096 + o * 64 + d];
    return;
  }
  i -= 8192;
  if (i < 5000) { int t = i / 200, ce = i % 200; dwT[i] = e2dw[ce * 25 + t]; }
}

// ---- posadd (block per (b,side)): X += tab; stats -> SM/SI ---------------
__global__ __launch_bounds__(1024) void k_posadd(float* __restrict__ XC, float* __restrict__ XQ,
                                                 const float* __restrict__ tab,
                                                 float* __restrict__ SMc, float* __restrict__ SIc,
                                                 float* __restrict__ SMq, float* __restrict__ SIq) {
  extern __shared__ float sm[];
  float* sX = sm; float* scratch = sm + 16384; float* smu = sm + 18432; float* sinv = sm + 18496;
  int b = blockIdx.x, side = blockIdx.y;
  float* X = side ? XQ : XC;
  int L = side ? 64 : 256;
  float* SM = side ? SMq : SMc;
  float* SI = side ? SIq : SIc;
  int tid = threadIdx.x;
  float* Xb = X + (size_t)b * 64 * L;
  for (int i = tid; i < 64 * L; i += 1024) {
    int d = i / L, l = i % L;
    float v = Xb[i] + tab[d * 256 + l];
    Xb[i] = v; sX[i] = v;
  }
  __syncthreads();
  block_stats(sX, scratch, smu, sinv, L, tid);
  if (tid < 64) { SM[b * 64 + tid] = smu[tid]; SI[b * 64 + tid] = sinv[tid]; }
}

// ---- fused conv pair (block per b): nconv x [norm->dw(K)->pw->relu->res] -
template<int K, int L>
__device__ void conv2_impl(float* __restrict__ sm, float* __restrict__ X,
                           const float* __restrict__ dw, const float* __restrict__ pw,
                           float* __restrict__ SM, float* __restrict__ SI, int b, int nconv) {
  constexpr int PER = (64 * L) / 1024;
  float* sX = sm; float* sD = sm + 16384; float* sW = sm + 32768;
  float* smu = sm + 36864; float* sinv = sm + 36928;
  int tid = threadIdx.x;
  int l = tid % L, og = tid / L;
  float* Xb = X + (size_t)b * 64 * L;
  for (int i = tid; i < 64 * L; i += 1024) sX[i] = Xb[i];
  if (tid < 64) { smu[tid] = SM[b * 64 + tid]; sinv[tid] = SI[b * 64 + tid]; }
  __syncthreads();
  for (int cv = 0; cv < nconv; ++cv) {
    {
      const float* pwc = pw + cv * 4096;
      for (int i = tid; i < 1024; i += 1024)
        ((float4*)sW)[i] = ((const float4*)pwc)[i];
    }
    for (int i = tid; i < 64 * L; i += 1024) {
      int c = i / L, ll = i % L;
      float mu = smu[c], iv = sinv[c];
      float acc = 0.f;
#pragma unroll
      for (int k = 0; k < K; ++k) {
        int p = ll + k - K / 2;
        float x = (p >= 0 && p < L) ? (sX[c * L + p] - mu) * iv : 0.f;
        acc += x * dw[cv * 64 * K + c * K + k];
      }
      sD[i] = acc;
    }
    __syncthreads();
    float acc[PER];
#pragma unroll
    for (int j = 0; j < PER; ++j) acc[j] = 0.f;
    for (int c = 0; c < 64; ++c) {
      float av = sD[c * L + l];
#pragma unroll
      for (int j = 0; j < PER; ++j) acc[j] += sW[(og * PER + j) * 64 + c] * av;
    }
#pragma unroll
    for (int j = 0; j < PER; ++j) {
      int o = og * PER + j;
      sX[o * L + l] = sX[o * L + l] + fmaxf(acc[j], 0.f);
    }
    __syncthreads();
    block_stats(sX, sD, smu, sinv, L, tid);
  }
  for (int i = tid; i < 64 * L; i += 1024) Xb[i] = sX[i];
  if (tid < 64) { SM[b * 64 + tid] = smu[tid]; SI[b * 64 + tid] = sinv[tid]; }
}

template<int K>
__global__ __launch_bounds__(1024) void k_conv2(
    float* XC, float* XQ,
    const float* dwC, const float* pwC, const float* dwQ, const float* pwQ,
    float* SMc, float* SIc, float* SMq, float* SIq, int nconv) {
  extern __shared__ float sm[];
  int b = blockIdx.x;
  if (blockIdx.y == 0) conv2_impl<K, 256>(sm, XC, dwC, pwC, SMc, SIc, b, nconv);
  else                 conv2_impl<K, 64>(sm, XQ, dwQ, pwQ, SMq, SIq, b, nconv);
}

// ---- fused wo + FF (block per b) -----------------------------------------
// mode 0: X = FF+tab, stats. mode 1: X = FF, Xnext = FF+tab, stats over FF+tab.
// mode 2: X = FF, no stats.
template<int L>
__device__ void woff_impl(float* __restrict__ sm, const float* __restrict__ U,
                          float* __restrict__ X, const float* __restrict__ wo,
                          const float* __restrict__ w, float* __restrict__ SM,
                          float* __restrict__ SI, float* __restrict__ Xnext,
                          const float* __restrict__ tab, int b, int mode) {
  constexpr int PER = (64 * L) / 1024;
  float* sX = sm; float* sD = sm + 16384; float* sW = sm + 32768;
  float* smu = sm + 36864; float* sinv = sm + 36928;
  int tid = threadIdx.x;
  int l = tid % L, og = tid / L;
  const float* Ub = U + (size_t)b * 64 * L;
  float* Xb = X + (size_t)b * 64 * L;
  for (int i = tid; i < 64 * L; i += 1024) { sX[i] = Ub[i]; sD[i] = Xb[i]; }
  {
    const float* Wb = wo + (size_t)b * 4096;
    for (int i = tid; i < 1024; i += 1024)
      ((float4*)sW)[i] = ((const float4*)Wb)[i];
  }
  __syncthreads();
  float acc[PER];
#pragma unroll
  for (int j = 0; j < PER; ++j) acc[j] = 0.f;
  for (int c = 0; c < 64; ++c) {
    float av = sX[c * L + l];
#pragma unroll
    for (int j = 0; j < PER; ++j) acc[j] += sW[(og * PER + j) * 64 + c] * av;
  }
  __syncthreads();
#pragma unroll
  for (int j = 0; j < PER; ++j) {
    int o = og * PER + j;
    sX[o * L + l] = sD[o * L + l] + acc[j];   // X' = X + wo.U (no relu)
  }
  __syncthreads();
  block_stats(sX, sD, smu, sinv, L, tid);     // stats of X'
  {
    const float* Wb = w + (size_t)b * 4096;
    for (int i = tid; i < 1024; i += 1024)
      ((float4*)sW)[i] = ((const float4*)Wb)[i];
  }
  __syncthreads();
#pragma unroll
  for (int j = 0; j < PER; ++j) acc[j] = 0.f;
  for (int c = 0; c < 64; ++c) {
    float av = (sX[c * L + l] - smu[c]) * sinv[c];
#pragma unroll
    for (int j = 0; j < PER; ++j) acc[j] += sW[(og * PER + j) * 64 + c] * av;
  }
  __syncthreads();
#pragma unroll
  for (int j = 0; j < PER; ++j) {
    int o = og * PER + j;
    float v = sX[o * L + l] + fmaxf(acc[j], 0.f);
    if (mode == 0) {
      float vn = v + tab[o * 256 + l];
      Xb[o * L + l] = vn; sX[o * L + l] = vn;
    } else if (mode == 1) {
      float vn = v + tab[o * 256 + l];
      Xb[o * L + l] = v;
      Xnext[(size_t)b * 64 * L + o * L + l] = vn;
      sX[o * L + l] = vn;
    } else {
      Xb[o * L + l] = v;
    }
  }
  if (mode < 2) {
    __syncthreads();
    block_stats(sX, sD, smu, sinv, L, tid);
    if (tid < 64) { SM[b * 64 + tid] = smu[tid]; SI[b * 64 + tid] = sinv[tid]; }
  }
}

__global__ __launch_bounds__(1024) void k_woff(
    const float* UC, const float* UQ, float* XC, float* XQ,
    const float* woC, const float* woQ, const float* wC, const float* wQ,
    float* SMc, float* SIc, float* SMq, float* SIq,
    float* Xnext, const float* tab, int mode) {
  extern __shared__ float sm[];
  int b = blockIdx.x;
  if (blockIdx.y == 0) woff_impl<256>(sm, UC, XC, woC, wC, SMc, SIc, Xnext, tab, b, mode);
  else                 woff_impl<64>(sm, UQ, XQ, woQ, wQ, SMq, SIq, nullptr, tab, b, mode);
}

// ---- resize (block per b): M0 = pw.dw5(Xcat) + tab ; stats -> SM/SI ------
__global__ __launch_bounds__(1024) void k_resize(
    const float* __restrict__ Xcat, const float* __restrict__ dw,
    const float* __restrict__ pw, const float* __restrict__ tab,
    float* __restrict__ out, float* __restrict__ SM, float* __restrict__ SI) {
  extern __shared__ float sm[];
  float* sA = sm; float* scratch = sm + 16384; float* smu = sm + 18432; float* sinv = sm + 18496;
  int b = blockIdx.x, tid = threadIdx.x;
  int l = tid & 255, og = tid >> 8;
  float acc[16];
#pragma unroll
  for (int j = 0; j < 16; ++j) acc[j] = 0.f;
  for (int c0 = 0; c0 < 256; c0 += 64) {
    __syncthreads();
    for (int i = tid; i < 16384; i += 1024) {
      int c = (i >> 8) + c0, ll = i & 255;
      const float* xr = Xcat + ((size_t)b * 256 + c) * 256;
      float a = 0.f;
#pragma unroll
      for (int k = 0; k < 5; ++k) {
        int p = ll + k - 2;
        if (p >= 0 && p < 256) a += xr[p] * dw[c * 5 + k];
      }
      sA[i] = a;
    }
    __syncthreads();
    for (int c = 0; c < 64; ++c) {
      float av = sA[c * 256 + l];
#pragma unroll
      for (int j = 0; j < 16; ++j)
        acc[j] += pw[(size_t)(og * 16 + j) * 256 + c0 + c] * av;
    }
  }
  __syncthreads();
#pragma unroll
  for (int j = 0; j < 16; ++j) {
    int o = og * 16 + j;
    float v = acc[j] + tab[o * 256 + l];
    out[((size_t)b * 64 + o) * 256 + l] = v;
    sA[o * 256 + l] = v;
  }
  __syncthreads();
  block_stats(sA, scratch, smu, sinv, 256, tid);
  if (tid < 64) { SM[b * 64 + tid] = smu[tid]; SI[b * 64 + tid] = sinv[tid]; }
}

// ---- self-attention; 1024 thr; 4-way split softmax; grid y: C then Q -----
__global__ __launch_bounds__(1024) void k_att(
    const float* __restrict__ XC, const float* __restrict__ SMc, const float* __restrict__ SIc,
    const float* __restrict__ wqC, const float* __restrict__ wkC,
    const float* __restrict__ wvC, float* __restrict__ hcC,
    const float* __restrict__ XQ, const float* __restrict__ SMq, const float* __restrict__ SIq,
    const float* __restrict__ wqQ, const float* __restrict__ wkQ,
    const float* __restrict__ wvQ, float* __restrict__ hcQ) {
  int h = blockIdx.x, b2 = blockIdx.y;
  const float *X, *SM, *SI, *wq, *wk, *wv; float* hc; int L, b;
  if (b2 < B) { X = XC; SM = SMc; SI = SIc; wq = wqC; wk = wkC; wv = wvC; hc = hcC; L = 256; b = b2; }
  else        { X = XQ; SM = SMq; SI = SIq; wq = wqQ; wk = wkQ; wv = wvQ; hc = hcQ; L = 64;  b = b2 - B; }
  __shared__ float smu[64], sinv[64];
  __shared__ float sX[64 * 65];
  __shared__ float sQ[2048], sK8[2048], sV[2048];
  __shared__ float swq[512], swk[512], swv[512];
  __shared__ float pmx[1024], psum[1024];
  int tid = threadIdx.x;
  if (tid < 64) { smu[tid] = SM[b * 64 + tid]; sinv[tid] = SI[b * 64 + tid]; }
  size_t woff = (size_t)(h * B + b) * 512;
  if (tid < 512) {
    swq[tid] = wq[woff + tid];
    swk[tid] = wk[woff + tid];
    swv[tid] = wv[woff + tid];
  }
  __syncthreads();
  const float* Xb = X + (size_t)b * 64 * L;
  for (int lt = 0; lt < L; lt += 64) {
    for (int i = tid; i < 4096; i += 1024) {
      int d = i >> 6, l = i & 63;
      sX[d * 65 + l] = (Xb[(size_t)d * L + lt + l] - smu[d]) * sinv[d];
    }
    __syncthreads();
    if (tid < 512) {
      int k = tid >> 6, l = tid & 63;
      float aq = 0.f, ak = 0.f, av = 0.f;
      for (int d = 0; d < 64; ++d) {
        float x = sX[d * 65 + l];
        aq += swq[k * 64 + d] * x;
        ak += swk[k * 64 + d] * x;
        av += swv[k * 64 + d] * x;
      }
      sQ[k * L + lt + l] = aq; sK8[k * L + lt + l] = ak; sV[k * L + lt + l] = av;
    }
    __syncthreads();
  }
  const float scale = 0.35355339059327373f;  // 1/sqrt(8)
  int m = tid & 255, qt = tid >> 8;
  int L4 = L >> 2;
  float mx = -1e30f, sum = 0.f, acc[8];
#pragma unroll
  for (int v = 0; v < 8; ++v) acc[v] = 0.f;
  if (m < L) {
    float kc[8];
#pragma unroll
    for (int k = 0; k < 8; ++k) kc[k] = sK8[k * L + m];
    int l0 = qt * L4, l1 = l0 + L4;
    for (int l = l0; l < l1; ++l) {
      float s = 0.f;
#pragma unroll
      for (int k = 0; k < 8; ++k) s += sQ[k * L + l] * kc[k];
      s *= scale;
      if (s <= mx) {
        float p = __expf(s - mx);
        sum += p;
#pragma unroll
        for (int v = 0; v < 8; ++v) acc[v] += p * sV[v * L + l];
      } else {
        float corr = __expf(mx - s);
        sum = sum * corr + 1.f;
#pragma unroll
        for (int v = 0; v < 8; ++v) acc[v] = acc[v] * corr + sV[v * L + l];
        mx = s;
      }
    }
  }
  float* pacc = sX;
  pmx[tid] = mx;
  psum[tid] = sum;
  __syncthreads();
  if (qt & 1) {
#pragma unroll
    for (int v = 0; v < 8; ++v) pacc[(((qt >> 1) << 8) + m) * 8 + v] = acc[v];
  }
  __syncthreads();
  if (!(qt & 1) && m < L) {
    float m1 = pmx[tid + 256], s1 = psum[tid + 256];
    float mT = fmaxf(mx, m1);
    float c0 = __expf(mx - mT), c1 = __expf(m1 - mT);
    sum = sum * c0 + s1 * c1;
#pragma unroll
    for (int v = 0; v < 8; ++v)
      acc[v] = acc[v] * c0 + pacc[(((qt >> 1) << 8) + m) * 8 + v] * c1;
    mx = mT;
  }
  __syncthreads();
  if (qt == 2) {
    pmx[512 + m] = mx;
    psum[512 + m] = sum;
#pragma unroll
    for (int v = 0; v < 8; ++v) pacc[m * 8 + v] = acc[v];
  }
  __syncthreads();
  if (qt == 0 && m < L) {
    float m1 = pmx[512 + m], s1 = psum[512 + m];
    float mT = fmaxf(mx, m1);
    float c0 = __expf(mx - mT), c1 = __expf(m1 - mT);
    float s = sum * c0 + s1 * c1;
    float is = 1.f / s;
#pragma unroll
    for (int v = 0; v < 8; ++v) {
      float a = acc[v] * c0 + pacc[m * 8 + v] * c1;
      hc[((size_t)b * 64 + h * 8 + v) * L + m] = a * is;
    }
  }
}

// ---- merged C+Q char embed: reg-staged taps + float4 LDS phase 2 ---------
__global__ __launch_bounds__(256) void k_charembed(
    const int* __restrict__ cidC, const int* __restrict__ cidQ,
    const float* __restrict__ ctab, const float* __restrict__ dwT,
    const float* __restrict__ db, const float* __restrict__ pwT,
    const float* __restrict__ pb,
    float* __restrict__ outC, float* __restrict__ outQ) {
  int nx = blockIdx.x, b = blockIdx.y;
  const int* cid; float* out; int Ln, n;
  if (nx < NN) { cid = cidC; out = outC; Ln = NN; n = nx; }
  else         { cid = cidQ; out = outQ; Ln = MQ; n = nx - NN; }
  __shared__ __align__(16) float dwo[16 * 200];
  __shared__ int sid[5][16];
  __shared__ float red[256];
  int tid = threadIdx.x;
  if (tid < 80) {
    int kn = tid / 16, cn = tid % 16;
    int nn = n + kn - 2;
    sid[kn][cn] = (nn >= 0 && nn < Ln) ? cid[((size_t)b * Ln + nn) * 16 + cn] : -1;
  }
  __syncthreads();
  for (int i = tid; i < 16 * 200; i += 256) {
    int cn = i / 200, ce = i % 200;
    float r[25];
#pragma unroll
    for (int kn = 0; kn < 5; ++kn) {
#pragma unroll
      for (int kc = 0; kc < 5; ++kc) {
        int cc = cn + kc - 2;
        int id = (cc >= 0 && cc < 16) ? sid[kn][cc] : -1;
        r[kn * 5 + kc] = (id >= 0) ? ctab[(size_t)id * 200 + ce] : 0.f;
      }
    }
    float acc = db[ce];
#pragma unroll
    for (int t = 0; t < 25; ++t) acc += r[t] * dwT[t * 200 + ce];
    dwo[cn * 200 + ce] = acc;
  }
  __syncthreads();
  int o = tid & 63, q = tid >> 6;
  float acc4[4];
#pragma unroll
  for (int k = 0; k < 4; ++k) acc4[k] = pb[o];
  for (int c0 = 0; c0 < 200; c0 += 8) {
    float w8[8];
#pragma unroll
    for (int j = 0; j < 8; ++j) w8[j] = pwT[(c0 + j) * 64 + o];
#pragma unroll
    for (int k = 0; k < 4; ++k) {
      const float* dr = dwo + (q + k * 4) * 200 + c0;
      float4 a0 = *(const float4*)dr;
      float4 a1 = *(const float4*)(dr + 4);
      acc4[k] += w8[0] * a0.x; acc4[k] += w8[1] * a0.y;
      acc4[k] += w8[2] * a0.z; acc4[k] += w8[3] * a0.w;
      acc4[k] += w8[4] * a1.x; acc4[k] += w8[5] * a1.y;
      acc4[k] += w8[6] * a1.z; acc4[k] += w8[7] * a1.w;
    }
  }
  float mx = -1e30f;
#pragma unroll
  for (int k = 0; k < 4; ++k) mx = fmaxf(mx, acc4[k]);
  red[tid] = mx;
  __syncthreads();
  if (q == 0) {
    mx = fmaxf(fmaxf(red[o], red[64 + o]), fmaxf(red[128 + o], red[192 + o]));
    out[((size_t)b * 64 + o) * Ln + n] = fmaxf(mx, 0.f);
  }
}

// ---- merged C+Q embconv + highway ----------------------------------------
__global__ void k_embhw(const float* __restrict__ chxC, const float* __restrict__ chxQ,
                        const int* __restrict__ widC, const int* __restrict__ widQ,
                        const float* __restrict__ wtab, const float* __restrict__ dw,
                        const float* __restrict__ db, const float* __restrict__ pwT,
                        const float* __restrict__ pb,
                        const float* __restrict__ lwT, const float* __restrict__ lb,
                        const float* __restrict__ gwT, const float* __restrict__ gb,
                        float* __restrict__ outC, float* __restrict__ outQ) {
  int nx = blockIdx.x, b = blockIdx.y;
  const float* chx; const int* wid; float* out; int Ln, n;
  if (nx < NN) { chx = chxC; wid = widC; out = outC; Ln = NN; n = nx; }
  else         { chx = chxQ; wid = widQ; out = outQ; Ln = MQ; n = nx - NN; }
  __shared__ float dwc[EC];
  __shared__ int sw[5];
  __shared__ float x[64], xn[64];
  int tid = threadIdx.x;
  if (tid < 5) {
    int nn = n + tid - 2;
    sw[tid] = (nn >= 0 && nn < Ln) ? wid[(size_t)b * Ln + nn] : -1;
  }
  __syncthreads();
  for (int ch = tid; ch < EC; ch += 64) {
    float r[5];
#pragma unroll
    for (int k = 0; k < 5; ++k) {
      int nn = n + k - 2;
      float v = 0.f;
      if (nn >= 0 && nn < Ln) {
        if (ch < 64) v = chx[((size_t)b * 64 + ch) * Ln + nn];
        else v = wtab[(size_t)sw[k] * 300 + (ch - 64)];
      }
      r[k] = v;
    }
    float acc = db[ch];
#pragma unroll
    for (int k = 0; k < 5; ++k) acc += r[k] * dw[ch * 5 + k];
    dwc[ch] = acc;
  }
  __syncthreads();
  int o = tid;
  float acc = pb[o];
  for (int c0 = 0; c0 < EC; c0 += 4) {
    float w4[4];
#pragma unroll
    for (int j = 0; j < 4; ++j) w4[j] = pwT[(c0 + j) * 64 + o];
#pragma unroll
    for (int j = 0; j < 4; ++j) acc += w4[j] * dwc[c0 + j];
  }
  x[o] = acc;
  __syncthreads();
  for (int layer = 0; layer < 2; ++layer) {
    const float* lwr = lwT + layer * 4096;
    const float* gwr = gwT + layer * 4096;
    float gl = gb[layer * 64 + o], nl = lb[layer * 64 + o];
    for (int d0 = 0; d0 < 64; d0 += 8) {
      float g8[8], l8[8];
#pragma unroll
      for (int j = 0; j < 8; ++j) { g8[j] = gwr[(d0 + j) * 64 + o]; l8[j] = lwr[(d0 + j) * 64 + o]; }
#pragma unroll
      for (int j = 0; j < 8; ++j) { gl += g8[j] * x[d0 + j]; nl += l8[j] * x[d0 + j]; }
    }
    float g = 1.f / (1.f + __expf(-gl));
    float r = fmaxf(nl, 0.f);
    xn[o] = g * r + (1.f - g) * x[o];
    __syncthreads();
    x[o] = xn[o];
    __syncthreads();
  }
  out[((size_t)b * 64 + o) * Ln + n] = x[o];
}

// ---------------- context-query attention ---------------------------------
__global__ __launch_bounds__(256) void k_cqS(const float* __restrict__ C,
                                             const float* __restrict__ Q,
                                             const float* __restrict__ w,
                                             float* __restrict__ S,
                                             float* __restrict__ rmax,
                                             float* __restrict__ rsum) {
  int b = blockIdx.x, nt = blockIdx.y * 64;
  __shared__ float sQ[4096], sC[4096], ct[64], qt[64], swb[192];
  const float* Cb = C + (size_t)b * 64 * 256;
  const float* Qb = Q + (size_t)b * 4096;
  const float* wb = w + (size_t)b * 192;
  if (threadIdx.x < 192) swb[threadIdx.x] = wb[threadIdx.x];
  for (int i = threadIdx.x; i < 4096; i += 256) {
    int d = i >> 6, m = i & 63;
    sQ[i] = Qb[d * 64 + m];
    sC[i] = Cb[d * 256 + nt + m];
  }
  __syncthreads();
  if (threadIdx.x < 64) {
    int j = threadIdx.x;
    float a = 0.f, c2 = 0.f;
    for (int d = 0; d < 64; ++d) {
      a += swb[64 + d] * sC[d * 64 + j];
      c2 += swb[d] * sQ[d * 64 + j];
    }
    ct[j] = a; qt[j] = c2;
  }
  __syncthreads();
  int m = threadIdx.x & 63, wv = threadIdx.x >> 6;
  for (int it = 0; it < 16; ++it) {
    int nl = wv + it * 4;
    float acc = ct[nl] + qt[m];
    for (int d = 0; d < 64; ++d)
      acc += sC[d * 64 + nl] * swb[128 + d] * sQ[d * 64 + m];
    S[((size_t)b * 256 + nt + nl) * 64 + m] = acc;
    float mx = acc;
#pragma unroll
    for (int o = 32; o > 0; o >>= 1) mx = fmaxf(mx, __shfl_xor(mx, o));
    float p = __expf(acc - mx);
#pragma unroll
    for (int o = 32; o > 0; o >>= 1) p += __shfl_xor(p, o);
    if (m == 0) { rmax[b * 256 + nt + nl] = mx; rsum[b * 256 + nt + nl] = p; }
  }
}

__global__ void k_cqcol(const float* __restrict__ S, float* __restrict__ cmax,
                        float* __restrict__ csum) {
  int b = blockIdx.x, m = threadIdx.x;
  const float* Sb = S + (size_t)b * 256 * 64;
  float mx = -1e30f;
  for (int n = 0; n < 256; ++n) mx = fmaxf(mx, Sb[n * 64 + m]);
  float s = 0.f;
  for (int n = 0; n < 256; ++n) s += __expf(Sb[n * 64 + m] - mx);
  cmax[b * 64 + m] = mx; csum[b * 64 + m] = s;
}

// ---- merged cqA (y=0..3) + cqCS2 (y=4) -----------------------------------
__global__ __launch_bounds__(256) void k_cqA_CS2(
    const float* __restrict__ C, const float* __restrict__ Q,
    const float* __restrict__ S, const float* __restrict__ rmax,
    const float* __restrict__ rsum, const float* __restrict__ cmax,
    const float* __restrict__ csum, float* __restrict__ Xcat,
    float* __restrict__ CS2) {
  __shared__ float sh[8256];
  int b = blockIdx.x, t = blockIdx.y;
  int tid = threadIdx.x;
  if (t < 4) {
    float* sQ = sh; float* sP = sh + 4096;
    int nt = t * 64;
    const float* Qb = Q + (size_t)b * 4096;
    for (int i = tid; i < 4096; i += 256) sQ[i] = Qb[i];
    for (int i = tid; i < 4096; i += 256) {
      int nl = i >> 6, m = i & 63;
      int n = nt + nl;
      sP[nl * 65 + m] = __expf(S[((size_t)b * 256 + n) * 64 + m] - rmax[b * 256 + n]) / rsum[b * 256 + n];
    }
    __syncthreads();
    int nl = tid & 63, dg = tid >> 6;
    int n = nt + nl;
    for (int j = 0; j < 16; ++j) {
      int d = dg * 16 + j;
      float acc = 0.f;
      for (int m = 0; m < 64; ++m) acc += sQ[d * 64 + m] * sP[nl * 65 + m];
      float cv = C[((size_t)b * 64 + d) * 256 + n];
      Xcat[((size_t)b * 256 + d) * 256 + n] = cv;
      Xcat[((size_t)b * 256 + 64 + d) * 256 + n] = acc;
      Xcat[((size_t)b * 256 + 128 + d) * 256 + n] = cv * acc;
    }
  } else {
    float* sP = sh; float* sC = sh + 4096;
    int m = tid & 63, dg = tid >> 6;
    float acc[16];
#pragma unroll
    for (int j = 0; j < 16; ++j) acc[j] = 0.f;
    for (int nt = 0; nt < 4; ++nt) {
      __syncthreads();
      for (int i = tid; i < 4096; i += 256) {
        int nl = i >> 6, mm = i & 63;
        int n = nt * 64 + nl;
        sP[i] = __expf(S[((size_t)b * 256 + n) * 64 + mm] - cmax[b * 64 + mm]) / csum[b * 64 + mm];
        int d = i >> 6, nn = i & 63;
        sC[i] = C[((size_t)b * 64 + d) * 256 + nt * 64 + nn];
      }
      __syncthreads();
      for (int nl = 0; nl < 64; ++nl) {
        float p = sP[nl * 64 + m];
#pragma unroll
        for (int j = 0; j < 16; ++j) acc[j] += sC[(dg * 16 + j) * 64 + nl] * p;
      }
    }
    for (int j = 0; j < 16; ++j)
      CS2[((size_t)b * 64 + dg * 16 + j) * 64 + m] = acc[j];
  }
}

// Bm[d,k] = sum_m CS2[d,m] * S1[k,m]
__global__ __launch_bounds__(256) void k_cqBm(
    const float* __restrict__ C, const float* __restrict__ CS2,
    const float* __restrict__ S, const float* __restrict__ rmax,
    const float* __restrict__ rsum, float* __restrict__ Xcat) {
  int b = blockIdx.x, kt = blockIdx.y * 64;
  __shared__ float sW[4096];
  __shared__ float sP[64 * 65];
  for (int i = threadIdx.x; i < 4096; i += 256) sW[i] = CS2[(size_t)b * 4096 + i];
  for (int i = threadIdx.x; i < 4096; i += 256) {
    int kl = i >> 6, m = i & 63;
    int k = kt + kl;
    sP[kl * 65 + m] = __expf(S[((size_t)b * 256 + k) * 64 + m] - rmax[b * 256 + k]) / rsum[b * 256 + k];
  }
  __syncthreads();
  int kl = threadIdx.x & 63, dg = threadIdx.x >> 6;
  int k = kt + kl;
  for (int j = 0; j < 16; ++j) {
    int d = dg * 16 + j;
    float acc = 0.f;
    for (int m = 0; m < 64; ++m) acc += sW[d * 64 + m] * sP[kl * 65 + m];
    float cv = C[((size_t)b * 64 + d) * 256 + k];
    Xcat[((size_t)b * 256 + 192 + d) * 256 + k] = cv * acc;
  }
}

// ---- both pointers in one launch: grid (B, 2) ----------------------------
__global__ void k_pointer2(const float* __restrict__ M0, const float* __restrict__ M1,
                           const float* __restrict__ M2, const float* __restrict__ w0,
                           const float* __restrict__ w1, float* __restrict__ out) {
  int b = blockIdx.x, sel = blockIdx.y, n = threadIdx.x;
  const float* wb = (sel ? w1 : w0) + b * 128;
  const float* Mb = sel ? M2 : M1;
  float y = 0.f;
  for (int d = 0; d < 64; ++d) {
    y += wb[d] * M0[((size_t)b * 64 + d) * 256 + n];
    y += wb[64 + d] * Mb[((size_t)b * 64 + d) * 256 + n];
  }
  __shared__ float wred[4], wsum[4];
  int lane = n & 63, wid = n >> 6;
  float mx = y;
#pragma unroll
  for (int o = 32; o > 0; o >>= 1) mx = fmaxf(mx, __shfl_xor(mx, o));
  if (lane == 0) wred[wid] = mx;
  __syncthreads();
  mx = fmaxf(fmaxf(wred[0], wred[1]), fmaxf(wred[2], wred[3]));
  float e = __expf(y - mx);
  float s = e;
#pragma unroll
  for (int o = 32; o > 0; o >>= 1) s += __shfl_xor(s, o);
  if (lane == 0) wsum[wid] = s;
  __syncthreads();
  s = wsum[0] + wsum[1] + wsum[2] + wsum[3];
  out[sel * 6144 + b * 256 + n] = e / s;
}

// ===========================================================================
extern "C" void kernel_launch(void* const* d_in, const int* in_sizes, int n_in,
                              void* d_out, int out_size, void* d_ws, size_t ws_size,
                              hipStream_t stream) {
  const float* word_table = (const float*)d_in[0];
  const float* char_table = (const float*)d_in[1];
  const float* e2dw = (const float*)d_in[2];
  const float* e2db = (const float*)d_in[3];
  const float* e2pw = (const float*)d_in[4];
  const float* e2pb = (const float*)d_in[5];
  const float* e1dw = (const float*)d_in[6];
  const float* e1db = (const float*)d_in[7];
  const float* e1pw = (const float*)d_in[8];
  const float* e1pb = (const float*)d_in[9];
  const float* hlw = (const float*)d_in[10];
  const float* hlb = (const float*)d_in[11];
  const float* hgw = (const float*)d_in[12];
  const float* hgb = (const float*)d_in[13];
  const float *enc_dw[5], *enc_pw[5], *enc_wq[5], *enc_wk[5], *enc_wv[5], *enc_wo[5], *enc_w[5];
  for (int p = 0; p < 5; ++p) {
    enc_dw[p] = (const float*)d_in[14 + 7 * p + 0];
    enc_pw[p] = (const float*)d_in[14 + 7 * p + 1];
    enc_wq[p] = (const float*)d_in[14 + 7 * p + 2];
    enc_wk[p] = (const float*)d_in[14 + 7 * p + 3];
    enc_wv[p] = (const float*)d_in[14 + 7 * p + 4];
    enc_wo[p] = (const float*)d_in[14 + 7 * p + 5];
    enc_w[p]  = (const float*)d_in[14 + 7 * p + 6];
  }
  const float* cq_w  = (const float*)d_in[49];
  const float* rs_dw = (const float*)d_in[50];
  const float* rs_pw = (const float*)d_in[51];
  const float* p_w0  = (const float*)d_in[52];
  const float* p_w1  = (const float*)d_in[53];
  const int* Cwid = (const int*)d_in[54];
  const int* Ccid = (const int*)d_in[55];
  const int* Qwid = (const int*)d_in[56];
  const int* Qcid = (const int*)d_in[57];
  float* out = (float*)d_out;

  // ---- workspace (floats) -------------------------------------------------
  float* ws = (float*)d_ws;
  float* postab = ws;                  // 16384
  float* U    = ws + 16384;            // 393216
  float* Xcat = ws + 409600;           // 1572864 ; M2 aliases; emb scratch
  float* CX   = ws + 1982464;          // 393216  ; M0 aliases
  float* Sb   = ws + 2375680;          // 393216  ; M1 aliases
  float* QX   = ws + 2768896;          // 98304
  float* CS2  = ws + 2867200;          // 98304
  float* rmax = ws + 2965504;          // 6144
  float* rsum = ws + 2971648;          // 6144
  float* cmax = ws + 2977792;          // 1536
  float* csum = ws + 2979328;          // 1536
  float* SMC  = ws + 2980864;          // 1536
  float* SIC  = ws + 2982400;          // 1536
  float* SMQ  = ws + 2983936;          // 1536
  float* SIQ  = ws + 2985472;          // 1536
  float* pwT  = ws + 3005440;          // 12800
  float* e1pwT= ws + 3018240;          // 23296
  float* hlwT = ws + 3041536;          // 8192
  float* hgwT = ws + 3049728;          // 8192
  float* dwT  = ws + 3057920;          // 5000
  float* UQ   = ws + 3087496;          // 98304 -> ends 3185800
  float* M0 = CX; float* M1 = Sb; float* M2 = Xcat;
  float* E1C = Xcat;              // 393216
  float* E1Q = Xcat + 393216;     // 98304
  (void)out_size; (void)in_sizes; (void)n_in; (void)ws_size;

  // model-stack encoder: stats pre-seeded in SMC/SIC, X pre-seeded
  auto run_enc = [&](float* X, float* Xnext, int p) {
    for (int rep = 0; rep < 7; ++rep) {
      hipLaunchKernelGGL((k_conv2<5>), dim3(B, 1), dim3(1024), CONV_LDS, stream,
                         X, (float*)nullptr, enc_dw[p], enc_pw[p],
                         (const float*)nullptr, (const float*)nullptr,
                         SMC, SIC, (float*)nullptr, (float*)nullptr, 2);
      k_att<<<dim3(HH, B), 1024, 0, stream>>>(X, SMC, SIC, enc_wq[p], enc_wk[p], enc_wv[p], U,
                                              (const float*)nullptr, (const float*)nullptr,
                                              (const float*)nullptr, (const float*)nullptr,
                                              (const float*)nullptr, (const float*)nullptr,
                                              (float*)nullptr);
      int mode = (rep < 6) ? 0 : (Xnext ? 1 : 2);
      hipLaunchKernelGGL(k_woff, dim3(B, 1), dim3(1024), CONV_LDS, stream,
                         (const float*)U, (const float*)nullptr, X, (float*)nullptr,
                         enc_wo[p], (const float*)nullptr, enc_w[p], (const float*)nullptr,
                         SMC, SIC, (float*)nullptr, (float*)nullptr,
                         Xnext, (const float*)postab, mode);
    }
  };

  k_prep<<<289, 256, 0, stream>>>(postab, e2pw, e1pw, hlw, hgw, e2dw,
                                  pwT, e1pwT, hlwT, hgwT, dwT);
  // ---- embeddings ----
  k_charembed<<<dim3(NN + MQ, B), 256, 0, stream>>>(Ccid, Qcid, char_table, dwT, e2db, pwT, e2pb, E1C, E1Q);
  k_embhw<<<dim3(NN + MQ, B), 64, 0, stream>>>(E1C, E1Q, Cwid, Qwid, word_table, e1dw, e1db,
                                               e1pwT, e1pb, hlwT, hlb, hgwT, hgb, CX, QX);
  // ---- embedding encoders (C and Q merged; 4 convs K=7) ----
  {
    hipLaunchKernelGGL(k_posadd, dim3(B, 2), dim3(1024), SMALL_LDS, stream,
                       CX, QX, (const float*)postab, SMC, SIC, SMQ, SIQ);
    hipLaunchKernelGGL((k_conv2<7>), dim3(B, 2), dim3(1024), CONV_LDS, stream,
                       CX, QX, enc_dw[0], enc_pw[0], enc_dw[1], enc_pw[1],
                       SMC, SIC, SMQ, SIQ, 2);
    hipLaunchKernelGGL((k_conv2<7>), dim3(B, 2), dim3(1024), CONV_LDS, stream,
                       CX, QX, enc_dw[0] + 2 * 64 * 7, enc_pw[0] + 2 * 4096,
                       enc_dw[1] + 2 * 64 * 7, enc_pw[1] + 2 * 4096,
                       SMC, SIC, SMQ, SIQ, 2);
    k_att<<<dim3(HH, 2 * B), 1024, 0, stream>>>(CX, SMC, SIC, enc_wq[0], enc_wk[0], enc_wv[0], U,
                                                QX, SMQ, SIQ, enc_wq[1], enc_wk[1], enc_wv[1], UQ);
    hipLaunchKernelGGL(k_woff, dim3(B, 2), dim3(1024), CONV_LDS, stream,
                       (const float*)U, (const float*)UQ, CX, QX,
                       enc_wo[0], enc_wo[1], enc_w[0], enc_w[1],
                       SMC, SIC, SMQ, SIQ,
                       (float*)nullptr, (const float*)postab, 2);
  }
  // ---- context-query attention ----
  k_cqS<<<dim3(B, 4), 256, 0, stream>>>(CX, QX, cq_w, Sb, rmax, rsum);
  k_cqcol<<<B, 64, 0, stream>>>(Sb, cmax, csum);
  k_cqA_CS2<<<dim3(B, 5), 256, 0, stream>>>(CX, QX, Sb, rmax, rsum, cmax, csum, Xcat, CS2);
  k_cqBm<<<dim3(B, 4), 256, 0, stream>>>(CX, CS2, Sb, rmax, rsum, Xcat);
  // ---- resize -> M0 (+tab +stats) ----
  hipLaunchKernelGGL(k_resize, dim3(B), dim3(1024), SMALL_LDS, stream,
                     (const float*)Xcat, rs_dw, rs_pw, (const float*)postab, M0, SMC, SIC);
  // ---- model encoders ----
  run_enc(M0, M1, 2);
  run_enc(M1, M2, 3);
  run_enc(M2, nullptr, 4);
  // ---- pointers ----
  k_pointer2<<<dim3(B, 2), 256, 0, stream>>>(M0, M1, M2, p_w0, p_w1, out);
}